// Round 1
// baseline (181.763 us; speedup 1.0000x reference)
//
#include <hip/hip_runtime.h>
#include <stdint.h>

#define PRIME 1000003u
#define NORD  1000002u
#define KCH   16
#define BATCH 4
#define NPATCH 784
#define LLEN  9
#define IPMAX 9000          // |<x,y>| <= 20*50*9
#define TBLN  (2*IPMAX+1)
#define NDEC  (KCH*BATCH*NPATCH)   // 50176 = 196 blocks * 256 threads exactly
#define NBLK  196                  // fused grid: all co-resident (196 < 256 CUs)

// Barrett: M = floor(2^41/p) = 2199016; exact for t < 2^40 with one cond-sub.
__device__ __forceinline__ uint32_t mmul(uint32_t a, uint32_t b) {
    uint64_t t = (uint64_t)a * (uint64_t)b;
    uint32_t q = (uint32_t)((t * 2199016ull) >> 41);
    uint32_t r = (uint32_t)t - q * PRIME;
    return (r >= PRIME) ? r - PRIME : r;
}

__device__ __forceinline__ uint32_t mpow(uint32_t base, uint32_t exp) {
    uint32_t r = 1u, b = base;
    while (exp) {
        if (exp & 1u) r = mmul(r, b);
        b = mmul(b, b);
        exp >>= 1;
    }
    return r;
}

// Device-scope grid barrier: release-add + acquire-spin by lane 0 of each
// block. Valid because all NBLK blocks are co-resident (196 blocks, 4 waves,
// 17.4 KB LDS each -> >=8 blocks/CU possible, 1 needed). Agent-scope
// release/acquire emit the L2 writeback/invalidate needed across XCDs.
__device__ __forceinline__ void gridbar(unsigned* ctr, unsigned target) {
    __syncthreads();
    if (threadIdx.x == 0) {
        __hip_atomic_fetch_add(ctr, 1u, __ATOMIC_RELEASE, __HIP_MEMORY_SCOPE_AGENT);
        while (__hip_atomic_load(ctr, __ATOMIC_ACQUIRE, __HIP_MEMORY_SCOPE_AGENT) < target)
            __builtin_amdgcn_s_sleep(2);
    }
    __syncthreads();
}

// ---------------- Kernel 1: dlog lookup table (int16) -----------------------
// table[g^e mod p] = e for e in [-9000,9000]; |e|<=9000 fits int16. Only
// queried entries are ever written (decrypted values are guaranteed g^e).
// Also zeroes the fused kernel's barrier counter (ws is re-poisoned between
// iterations, so this must happen every launch; the kernel boundary orders it).
__global__ void build_table(const int* __restrict__ g_in, int16_t* __restrict__ table,
                            unsigned* __restrict__ ctr) {
    int e = blockIdx.x * blockDim.x + threadIdx.x;
    if (e >= TBLN) return;
    if (e == 0) *ctr = 0u;
    int es = e - IPMAX;
    uint32_t exp = (es >= 0) ? (uint32_t)es : (uint32_t)(es + (int)NORD);
    table[mpow((uint32_t)g_in[0], exp)] = (int16_t)es;
}

// ---------------- Kernel 2: fused decrypt + conv2 + conv3 + fc --------------
// 196 blocks x 256 threads, phases separated by device-scope grid barriers:
//   A: IPFE decrypt + table dlog + bias1+bn1+relu        (all 196 blocks)
//   B: pool(28->14)+conv2+bn2+relu+pool(14->7)           (blocks 0..127)
//   C: conv3+bn3+relu+pool(7->3), 4 oc per block         (blocks 0..63)
//   D: fc1+relu+fc2                                      (blocks 0..3)
// Replaces 4 separate dispatches: 3 graph-node boundaries -> 3 in-kernel
// barriers (~1-2us each vs ~2-4us per node gap).
__global__ void __launch_bounds__(256) fused(
    const int* __restrict__ ct0, const int* __restrict__ cts,
    const int* __restrict__ y, const int* __restrict__ sk_y,
    const float* __restrict__ bias1,
    const float* __restrict__ bn1_g, const float* __restrict__ bn1_b,
    const float* __restrict__ bn1_m, const float* __restrict__ bn1_v,
    const float* __restrict__ conv2_w, const float* __restrict__ conv2_b,
    const float* __restrict__ bn2_g, const float* __restrict__ bn2_b,
    const float* __restrict__ bn2_m, const float* __restrict__ bn2_v,
    const float* __restrict__ conv3_w, const float* __restrict__ conv3_b,
    const float* __restrict__ bn3_g, const float* __restrict__ bn3_b,
    const float* __restrict__ bn3_m, const float* __restrict__ bn3_v,
    const float* __restrict__ fc1_w, const float* __restrict__ fc1_b,
    const float* __restrict__ fc2_w, const float* __restrict__ fc2_b,
    const int16_t* __restrict__ table,
    float* __restrict__ featr, float* __restrict__ s2g, float* __restrict__ s3g,
    float* __restrict__ out, unsigned* __restrict__ ctr) {

    __shared__ union {
        struct { float s1p[16][16][16]; float w[144]; float co[196]; } c2;   // 17.7 KB
        struct { float s2p[32][9][9];  float w[4][288]; float co[4][49]; } c3; // 15.8 KB
        struct { float s3[576]; float h[128]; } fc;                          // 2.8 KB
    } sm;

    const int bid = blockIdx.x;
    const int tid = threadIdx.x;

    // ---------------- Phase A: decrypt (all blocks; 196*256 == NDEC) -------
    {
        int gtid = bid * 256 + tid;
        // 3136 = 49 full waves per k -> k is wave-uniform; force scalarization.
        int k = __builtin_amdgcn_readfirstlane(gtid / (BATCH * NPATCH));
        int r = gtid % (BATCH * NPATCH);
        int b = r / NPATCH;
        int j = r % NPATCH;

        const int* crow = cts + ((b * NPATCH) + j) * LLEN;
        const int* yrow = y + k * LLEN;

        uint32_t c[LLEN];
        int yv[LLEN];
#pragma unroll
        for (int i = 0; i < LLEN; i++) {
            yv[i] = yrow[i];                  // scalar loads (k wave-uniform)
            c[i]  = (uint32_t)crow[i];        // vector loads
        }

        // Shamir: |y_i| <= 50 < 64 (6 bits). Branch conds are wave-uniform.
        uint32_t accp = 1u, accn = 1u;
#pragma unroll
        for (int bit = 5; bit >= 0; bit--) {
            accp = mmul(accp, accp);
            accn = mmul(accn, accn);
#pragma unroll
            for (int i = 0; i < LLEN; i++) {
                int yi = yv[i];
                int ay = (yi > 0) ? yi : -yi;
                if ((ay >> bit) & 1) {
                    if (yi > 0) accp = mmul(accp, c[i]);
                    else        accn = mmul(accn, c[i]);
                }
            }
        }

        uint32_t den = mpow((uint32_t)ct0[b * NPATCH + j], (uint32_t)sk_y[k]);
        den = mmul(den, accn);
        uint32_t val = mmul(accp, mpow(den, PRIME - 2u));  // const exp: unrolls

        int ip = (int)table[val];              // guaranteed hit, |ip|<=9000

        float sc = bn1_g[k] * rsqrtf(bn1_v[k] + 1e-5f);
        float shf = (bias1[k] - bn1_m[k]) * sc + bn1_b[k];
        float v_ = fmaf((float)ip, sc * 1e-4f, shf);
        featr[((b * KCH) + k) * NPATCH + j] = fmaxf(v_, 0.0f);
    }

    gridbar(ctr, NBLK);          // featr complete

    // ---------------- Phase B: pool + conv2 + bn2 + relu + pool ------------
    if (bid < 128) {
        const int b  = bid >> 5;
        const int oc = bid & 31;

        for (int i = tid; i < 16 * 16 * 16; i += 256)
            ((float*)sm.c2.s1p)[i] = 0.0f;
        if (tid < 144) sm.c2.w[tid] = conv2_w[oc * 144 + tid];
        __syncthreads();
        for (int i = tid; i < 16 * 196; i += 256) {
            int ic = i / 196, pos = i % 196;
            int yy = pos / 14, xx = pos % 14;
            const float* fp = featr + ((b * 16 + ic) * 784) + (2 * yy) * 28 + 2 * xx;
            sm.c2.s1p[ic][yy + 1][xx + 1] = fmaxf(fmaxf(fp[0], fp[1]), fmaxf(fp[28], fp[29]));
        }
        __syncthreads();

        if (tid < 196) {
            int oh = tid / 14, ow = tid % 14;
            float a0 = 0.0f, a1 = 0.0f, a2 = 0.0f;
#pragma unroll
            for (int ic = 0; ic < 16; ic++) {
                const float* wp = &sm.c2.w[ic * 9];
                const float* sp = &sm.c2.s1p[ic][oh][ow];
                a0 = fmaf(sp[0],  wp[0], fmaf(sp[1],  wp[1], fmaf(sp[2],  wp[2], a0)));
                a1 = fmaf(sp[16], wp[3], fmaf(sp[17], wp[4], fmaf(sp[18], wp[5], a1)));
                a2 = fmaf(sp[32], wp[6], fmaf(sp[33], wp[7], fmaf(sp[34], wp[8], a2)));
            }
            float sc = bn2_g[oc] * rsqrtf(bn2_v[oc] + 1e-5f);
            float shf = bn2_b[oc] - bn2_m[oc] * sc;
            sm.c2.co[tid] = fmaxf((a0 + a1 + a2 + conv2_b[oc]) * sc + shf, 0.0f);
        }
        __syncthreads();

        if (tid < 49) {
            int oh = tid / 7, ow = tid % 7;
            const float* c0 = &sm.c2.co[(2 * oh) * 14 + 2 * ow];
            s2g[((b * 32 + oc) * 49) + tid] =
                fmaxf(fmaxf(c0[0], c0[1]), fmaxf(c0[14], c0[15]));
        }
    }

    gridbar(ctr, 2 * NBLK);      // s2g complete

    // ---------------- Phase C: conv3 + bn3 + relu + pool (4 oc / block) ----
    if (bid < 64) {
        const int b = bid >> 4, ocg = bid & 15;

        for (int i = tid; i < 32 * 81; i += 256)
            ((float*)sm.c3.s2p)[i] = 0.0f;
        for (int i = tid; i < 4 * 288; i += 256) {
            int w2 = i / 288, rr = i % 288;
            sm.c3.w[w2][rr] = conv3_w[(ocg * 4 + w2) * 288 + rr];
        }
        __syncthreads();
        for (int i = tid; i < 32 * 49; i += 256) {
            int ic = i / 49, pos = i % 49;
            sm.c3.s2p[ic][pos / 7 + 1][pos % 7 + 1] = s2g[((b * 32 + ic) * 49) + pos];
        }
        __syncthreads();

        const int wid = tid >> 6, lane = tid & 63;
        if (lane < 49) {
            int oh = lane / 7, ow = lane % 7;
            float a0 = 0.0f, a1 = 0.0f, a2 = 0.0f;
#pragma unroll
            for (int ic = 0; ic < 32; ic++) {
                const float* wp = &sm.c3.w[wid][ic * 9];
                const float* sp = &sm.c3.s2p[ic][oh][ow];
                a0 = fmaf(sp[0],  wp[0], fmaf(sp[1],  wp[1], fmaf(sp[2],  wp[2], a0)));
                a1 = fmaf(sp[9],  wp[3], fmaf(sp[10], wp[4], fmaf(sp[11], wp[5], a1)));
                a2 = fmaf(sp[18], wp[6], fmaf(sp[19], wp[7], fmaf(sp[20], wp[8], a2)));
            }
            int oc = ocg * 4 + wid;
            float sc = bn3_g[oc] * rsqrtf(bn3_v[oc] + 1e-5f);
            float shf = bn3_b[oc] - bn3_m[oc] * sc;
            sm.c3.co[wid][lane] = fmaxf((a0 + a1 + a2 + conv3_b[oc]) * sc + shf, 0.0f);
        }
        __syncthreads();

        if (tid < 36) {
            int w2 = tid / 9, p = tid % 9;
            int oh = p / 3, ow = p % 3;
            const float* c0 = &sm.c3.co[w2][(2 * oh) * 7 + 2 * ow];
            s3g[b * 576 + (ocg * 4 + w2) * 9 + p] =
                fmaxf(fmaxf(c0[0], c0[1]), fmaxf(c0[7], c0[8]));
        }
    }

    gridbar(ctr, 3 * NBLK);      // s3g complete

    // ---------------- Phase D: fc1 + relu + fc2 ----------------------------
    if (bid < BATCH) {
        const int b = bid;
        for (int i = tid; i < 576; i += 256) sm.fc.s3[i] = s3g[b * 576 + i];
        __syncthreads();

        const int wid = tid >> 6, lane = tid & 63;
        for (int oo = 0; oo < 32; oo++) {
            int o = wid * 32 + oo;
            const float* w = fc1_w + o * 576;
            float acc = 0.0f;
#pragma unroll
            for (int jj = 0; jj < 9; jj++)     // lanes across 576: coalesced
                acc = fmaf(sm.fc.s3[jj * 64 + lane], w[jj * 64 + lane], acc);
#pragma unroll
            for (int off = 32; off; off >>= 1) acc += __shfl_down(acc, off);
            if (lane == 0) sm.fc.h[o] = fmaxf(acc + fc1_b[o], 0.0f);
        }
        __syncthreads();

        for (int o = wid; o < 10; o += 4) {
            const float* w = fc2_w + o * 128;
            float acc = fmaf(sm.fc.h[lane], w[lane], 0.0f);
            acc = fmaf(sm.fc.h[64 + lane], w[64 + lane], acc);
#pragma unroll
            for (int off = 32; off; off >>= 1) acc += __shfl_down(acc, off);
            if (lane == 0) out[b * 10 + o] = acc + fc2_b[o];
        }
    }
}

extern "C" void kernel_launch(void* const* d_in, const int* in_sizes, int n_in,
                              void* d_out, int out_size, void* d_ws, size_t ws_size,
                              hipStream_t stream) {
    const int*   ct0    = (const int*)d_in[0];
    const int*   cts    = (const int*)d_in[1];
    const int*   y      = (const int*)d_in[2];
    const int*   sk_y   = (const int*)d_in[3];
    const float* bias1  = (const float*)d_in[4];
    const float* bn1_g  = (const float*)d_in[5];
    const float* bn1_b  = (const float*)d_in[6];
    const float* bn1_m  = (const float*)d_in[7];
    const float* bn1_v  = (const float*)d_in[8];
    const float* conv2_w = (const float*)d_in[9];
    const float* conv2_b = (const float*)d_in[10];
    const float* bn2_g  = (const float*)d_in[11];
    const float* bn2_b  = (const float*)d_in[12];
    const float* bn2_m  = (const float*)d_in[13];
    const float* bn2_v  = (const float*)d_in[14];
    const float* conv3_w = (const float*)d_in[15];
    const float* conv3_b = (const float*)d_in[16];
    const float* bn3_g  = (const float*)d_in[17];
    const float* bn3_b  = (const float*)d_in[18];
    const float* bn3_m  = (const float*)d_in[19];
    const float* bn3_v  = (const float*)d_in[20];
    const float* fc1_w  = (const float*)d_in[21];
    const float* fc1_b  = (const float*)d_in[22];
    const float* fc2_w  = (const float*)d_in[23];
    const float* fc2_b  = (const float*)d_in[24];
    const int*   g_in   = (const int*)d_in[25];
    float* out = (float*)d_out;

    // Workspace layout (bytes):
    //   [0,        2000006)  int16 dlog table (p entries)
    //   [2000064,  2000068)  unsigned barrier counter (re-zeroed by build_table)
    //   [2000128,  2200832)  float featr [4][16][28][28]
    //   [2200832,  2225920)  float s2g   [4][32][7][7]
    //   [2225920,  2235136)  float s3g   [4][576]
    char* ws = (char*)d_ws;
    int16_t*  table = (int16_t*)ws;
    unsigned* ctr   = (unsigned*)(ws + 2000064);
    float* featr = (float*)(ws + 2000128);
    float* s2g   = (float*)(ws + 2200832);
    float* s3g   = (float*)(ws + 2225920);

    build_table<<<(TBLN + 255) / 256, 256, 0, stream>>>(g_in, table, ctr);

    fused<<<NBLK, 256, 0, stream>>>(
        ct0, cts, y, sk_y, bias1, bn1_g, bn1_b, bn1_m, bn1_v,
        conv2_w, conv2_b, bn2_g, bn2_b, bn2_m, bn2_v,
        conv3_w, conv3_b, bn3_g, bn3_b, bn3_m, bn3_v,
        fc1_w, fc1_b, fc2_w, fc2_b, table, featr, s2g, s3g, out, ctr);
}

// Round 2
// 158.452 us; speedup vs baseline: 1.1471x; 1.1471x over previous
//
#include <hip/hip_runtime.h>
#include <stdint.h>

#define PRIME 1000003u
#define NORD  1000002u
#define KCH   16
#define BATCH 4
#define NPATCH 784
#define LLEN  9
#define IPMAX 9000          // |<x,y>| <= 20*50*9
#define TBLN  (2*IPMAX+1)
#define NDEC  (KCH*BATCH*NPATCH)   // 50176 = 196 blocks * 256 threads exactly
#define NBLK  196                  // fused grid: all co-resident (196 < 256 CUs)

// Barrett: M = floor(2^41/p) = 2199016; exact for t < 2^40 with one cond-sub.
__device__ __forceinline__ uint32_t mmul(uint32_t a, uint32_t b) {
    uint64_t t = (uint64_t)a * (uint64_t)b;
    uint32_t q = (uint32_t)((t * 2199016ull) >> 41);
    uint32_t r = (uint32_t)t - q * PRIME;
    return (r >= PRIME) ? r - PRIME : r;
}

__device__ __forceinline__ uint32_t mpow(uint32_t base, uint32_t exp) {
    uint32_t r = 1u, b = base;
    while (exp) {
        if (exp & 1u) r = mmul(r, b);
        b = mmul(b, b);
        exp >>= 1;
    }
    return r;
}

// ---- Fence-free cross-phase data access -----------------------------------
// Relaxed agent-scope atomics compile to coherent (L2-bypassing) global
// loads/stores on gfx950. Stores are acked at the device coherence point by
// the vmcnt(0) inside __syncthreads(); loads cannot hit a stale local L2.
// This replaces release/acquire fences (buffer_wbl2 / buffer_inv), which cost
// ~20us per grid barrier in the previous round (196 L2 writebacks/barrier).
__device__ __forceinline__ void cstore(float* p, float v) {
    __hip_atomic_store(p, v, __ATOMIC_RELAXED, __HIP_MEMORY_SCOPE_AGENT);
}
__device__ __forceinline__ float cload(const float* p) {
    return __hip_atomic_load(p, __ATOMIC_RELAXED, __HIP_MEMORY_SCOPE_AGENT);
}

// Fence-free grid barrier: relaxed arrive + relaxed spin. Valid because all
// NBLK blocks are co-resident (196 blocks < 256 CUs, 4 waves, 17.9 KB LDS).
__device__ __forceinline__ void arrive(unsigned* ctr) {
    __syncthreads();   // all block stores issued+acked (vmcnt 0) before add
    if (threadIdx.x == 0)
        __hip_atomic_fetch_add(ctr, 1u, __ATOMIC_RELAXED, __HIP_MEMORY_SCOPE_AGENT);
}
__device__ __forceinline__ void wait_ctr(unsigned* ctr, unsigned target) {
    if (threadIdx.x == 0)
        while (__hip_atomic_load(ctr, __ATOMIC_RELAXED, __HIP_MEMORY_SCOPE_AGENT) < target)
            __builtin_amdgcn_s_sleep(2);
    __syncthreads();
}

// ---------------- Kernel 1: dlog lookup table (int16) -----------------------
// table[g^e mod p] = e for e in [-9000,9000]; |e|<=9000 fits int16. Only
// queried entries are ever written (decrypted values are guaranteed g^e).
// Also zeroes the fused kernel's barrier counter (ws is re-poisoned between
// iterations); the kernel boundary orders it before the fused kernel.
__global__ void build_table(const int* __restrict__ g_in, int16_t* __restrict__ table,
                            unsigned* __restrict__ ctr) {
    int e = blockIdx.x * blockDim.x + threadIdx.x;
    if (e >= TBLN) return;
    if (e == 0)
        __hip_atomic_store(ctr, 0u, __ATOMIC_RELAXED, __HIP_MEMORY_SCOPE_AGENT);
    int es = e - IPMAX;
    uint32_t exp = (es >= 0) ? (uint32_t)es : (uint32_t)(es + (int)NORD);
    table[mpow((uint32_t)g_in[0], exp)] = (int16_t)es;
}

// ---------------- Kernel 2: fused decrypt + conv2 + conv3 + fc --------------
// 196 blocks x 256 threads, phases separated by fence-free grid barriers:
//   A: IPFE decrypt + table dlog + bias1+bn1+relu        (all 196 blocks)
//   B: pool(28->14)+conv2+bn2+relu+pool(14->7)           (blocks 0..127)
//   C: conv3+bn3+relu+pool(7->3), 4 oc per block         (blocks 0..63)
//   D: fc1+relu+fc2                                      (blocks 0..3)
// Cumulative barrier targets (196/324/388) let finished blocks exit early.
__global__ void __launch_bounds__(256) fused(
    const int* __restrict__ ct0, const int* __restrict__ cts,
    const int* __restrict__ y, const int* __restrict__ sk_y,
    const float* __restrict__ bias1,
    const float* __restrict__ bn1_g, const float* __restrict__ bn1_b,
    const float* __restrict__ bn1_m, const float* __restrict__ bn1_v,
    const float* __restrict__ conv2_w, const float* __restrict__ conv2_b,
    const float* __restrict__ bn2_g, const float* __restrict__ bn2_b,
    const float* __restrict__ bn2_m, const float* __restrict__ bn2_v,
    const float* __restrict__ conv3_w, const float* __restrict__ conv3_b,
    const float* __restrict__ bn3_g, const float* __restrict__ bn3_b,
    const float* __restrict__ bn3_m, const float* __restrict__ bn3_v,
    const float* __restrict__ fc1_w, const float* __restrict__ fc1_b,
    const float* __restrict__ fc2_w, const float* __restrict__ fc2_b,
    const int16_t* __restrict__ table,
    float* __restrict__ featr, float* __restrict__ s2g, float* __restrict__ s3g,
    float* __restrict__ out, unsigned* __restrict__ ctr) {

    __shared__ union {
        struct { float s1p[16][16][16]; float w[144]; float co[196]; } c2;   // 17.7 KB
        struct { float s2p[32][9][9];  float w[4][288]; float co[4][49]; } c3; // 15.8 KB
        struct { float s3[576]; float h[128]; } fc;                          // 2.8 KB
    } sm;

    const int bid = blockIdx.x;
    const int tid = threadIdx.x;

    // ---------------- Phase A: decrypt (all blocks; 196*256 == NDEC) -------
    {
        int gtid = bid * 256 + tid;
        // 3136 = 49 full waves per k -> k is wave-uniform; force scalarization.
        int k = __builtin_amdgcn_readfirstlane(gtid / (BATCH * NPATCH));
        int r = gtid % (BATCH * NPATCH);
        int b = r / NPATCH;
        int j = r % NPATCH;

        const int* crow = cts + ((b * NPATCH) + j) * LLEN;
        const int* yrow = y + k * LLEN;

        uint32_t c[LLEN];
        int yv[LLEN];
#pragma unroll
        for (int i = 0; i < LLEN; i++) {
            yv[i] = yrow[i];                  // scalar loads (k wave-uniform)
            c[i]  = (uint32_t)crow[i];        // vector loads
        }

        // Shamir: |y_i| <= 50 < 64 (6 bits). Branch conds are wave-uniform.
        uint32_t accp = 1u, accn = 1u;
#pragma unroll
        for (int bit = 5; bit >= 0; bit--) {
            accp = mmul(accp, accp);
            accn = mmul(accn, accn);
#pragma unroll
            for (int i = 0; i < LLEN; i++) {
                int yi = yv[i];
                int ay = (yi > 0) ? yi : -yi;
                if ((ay >> bit) & 1) {
                    if (yi > 0) accp = mmul(accp, c[i]);
                    else        accn = mmul(accn, c[i]);
                }
            }
        }

        uint32_t den = mpow((uint32_t)ct0[b * NPATCH + j], (uint32_t)sk_y[k]);
        den = mmul(den, accn);
        uint32_t val = mmul(accp, mpow(den, PRIME - 2u));  // const exp: unrolls

        int ip = (int)table[val];              // guaranteed hit, |ip|<=9000

        float sc = bn1_g[k] * rsqrtf(bn1_v[k] + 1e-5f);
        float shf = (bias1[k] - bn1_m[k]) * sc + bn1_b[k];
        float v_ = fmaf((float)ip, sc * 1e-4f, shf);
        cstore(&featr[((b * KCH) + k) * NPATCH + j], fmaxf(v_, 0.0f));
    }

    arrive(ctr);                       // -> 196 when featr complete
    if (bid >= 128) return;
    wait_ctr(ctr, NBLK);

    // ---------------- Phase B: pool + conv2 + bn2 + relu + pool ------------
    {
        const int b  = bid >> 5;
        const int oc = bid & 31;

        for (int i = tid; i < 16 * 16 * 16; i += 256)
            ((float*)sm.c2.s1p)[i] = 0.0f;
        if (tid < 144) sm.c2.w[tid] = conv2_w[oc * 144 + tid];
        __syncthreads();
        for (int i = tid; i < 16 * 196; i += 256) {
            int ic = i / 196, pos = i % 196;
            int yy = pos / 14, xx = pos % 14;
            const float* fp = featr + ((b * 16 + ic) * 784) + (2 * yy) * 28 + 2 * xx;
            sm.c2.s1p[ic][yy + 1][xx + 1] =
                fmaxf(fmaxf(cload(fp + 0), cload(fp + 1)),
                      fmaxf(cload(fp + 28), cload(fp + 29)));
        }
        __syncthreads();

        if (tid < 196) {
            int oh = tid / 14, ow = tid % 14;
            float a0 = 0.0f, a1 = 0.0f, a2 = 0.0f;
#pragma unroll
            for (int ic = 0; ic < 16; ic++) {
                const float* wp = &sm.c2.w[ic * 9];
                const float* sp = &sm.c2.s1p[ic][oh][ow];
                a0 = fmaf(sp[0],  wp[0], fmaf(sp[1],  wp[1], fmaf(sp[2],  wp[2], a0)));
                a1 = fmaf(sp[16], wp[3], fmaf(sp[17], wp[4], fmaf(sp[18], wp[5], a1)));
                a2 = fmaf(sp[32], wp[6], fmaf(sp[33], wp[7], fmaf(sp[34], wp[8], a2)));
            }
            float sc = bn2_g[oc] * rsqrtf(bn2_v[oc] + 1e-5f);
            float shf = bn2_b[oc] - bn2_m[oc] * sc;
            sm.c2.co[tid] = fmaxf((a0 + a1 + a2 + conv2_b[oc]) * sc + shf, 0.0f);
        }
        __syncthreads();

        if (tid < 49) {
            int oh = tid / 7, ow = tid % 7;
            const float* c0 = &sm.c2.co[(2 * oh) * 14 + 2 * ow];
            cstore(&s2g[((b * 32 + oc) * 49) + tid],
                   fmaxf(fmaxf(c0[0], c0[1]), fmaxf(c0[14], c0[15])));
        }
    }

    arrive(ctr);                       // -> 324 when s2g complete
    if (bid >= 64) return;
    wait_ctr(ctr, NBLK + 128);

    // ---------------- Phase C: conv3 + bn3 + relu + pool (4 oc / block) ----
    {
        const int b = bid >> 4, ocg = bid & 15;

        for (int i = tid; i < 32 * 81; i += 256)
            ((float*)sm.c3.s2p)[i] = 0.0f;
        for (int i = tid; i < 4 * 288; i += 256) {
            int w2 = i / 288, rr = i % 288;
            sm.c3.w[w2][rr] = conv3_w[(ocg * 4 + w2) * 288 + rr];
        }
        __syncthreads();
        for (int i = tid; i < 32 * 49; i += 256) {
            int ic = i / 49, pos = i % 49;
            sm.c3.s2p[ic][pos / 7 + 1][pos % 7 + 1] = cload(&s2g[((b * 32 + ic) * 49) + pos]);
        }
        __syncthreads();

        const int wid = tid >> 6, lane = tid & 63;
        if (lane < 49) {
            int oh = lane / 7, ow = lane % 7;
            float a0 = 0.0f, a1 = 0.0f, a2 = 0.0f;
#pragma unroll
            for (int ic = 0; ic < 32; ic++) {
                const float* wp = &sm.c3.w[wid][ic * 9];
                const float* sp = &sm.c3.s2p[ic][oh][ow];
                a0 = fmaf(sp[0],  wp[0], fmaf(sp[1],  wp[1], fmaf(sp[2],  wp[2], a0)));
                a1 = fmaf(sp[9],  wp[3], fmaf(sp[10], wp[4], fmaf(sp[11], wp[5], a1)));
                a2 = fmaf(sp[18], wp[6], fmaf(sp[19], wp[7], fmaf(sp[20], wp[8], a2)));
            }
            int oc = ocg * 4 + wid;
            float sc = bn3_g[oc] * rsqrtf(bn3_v[oc] + 1e-5f);
            float shf = bn3_b[oc] - bn3_m[oc] * sc;
            sm.c3.co[wid][lane] = fmaxf((a0 + a1 + a2 + conv3_b[oc]) * sc + shf, 0.0f);
        }
        __syncthreads();

        if (tid < 36) {
            int w2 = tid / 9, p = tid % 9;
            int oh = p / 3, ow = p % 3;
            const float* c0 = &sm.c3.co[w2][(2 * oh) * 7 + 2 * ow];
            cstore(&s3g[b * 576 + (ocg * 4 + w2) * 9 + p],
                   fmaxf(fmaxf(c0[0], c0[1]), fmaxf(c0[7], c0[8])));
        }
    }

    arrive(ctr);                       // -> 388 when s3g complete
    if (bid >= BATCH) return;
    wait_ctr(ctr, NBLK + 128 + 64);

    // ---------------- Phase D: fc1 + relu + fc2 ----------------------------
    {
        const int b = bid;
        for (int i = tid; i < 576; i += 256) sm.fc.s3[i] = cload(&s3g[b * 576 + i]);
        __syncthreads();

        const int wid = tid >> 6, lane = tid & 63;
        for (int oo = 0; oo < 32; oo++) {
            int o = wid * 32 + oo;
            const float* w = fc1_w + o * 576;
            float acc = 0.0f;
#pragma unroll
            for (int jj = 0; jj < 9; jj++)     // lanes across 576: coalesced
                acc = fmaf(sm.fc.s3[jj * 64 + lane], w[jj * 64 + lane], acc);
#pragma unroll
            for (int off = 32; off; off >>= 1) acc += __shfl_down(acc, off);
            if (lane == 0) sm.fc.h[o] = fmaxf(acc + fc1_b[o], 0.0f);
        }
        __syncthreads();

        for (int o = wid; o < 10; o += 4) {
            const float* w = fc2_w + o * 128;
            float acc = fmaf(sm.fc.h[lane], w[lane], 0.0f);
            acc = fmaf(sm.fc.h[64 + lane], w[64 + lane], acc);
#pragma unroll
            for (int off = 32; off; off >>= 1) acc += __shfl_down(acc, off);
            if (lane == 0) out[b * 10 + o] = acc + fc2_b[o];
        }
    }
}

extern "C" void kernel_launch(void* const* d_in, const int* in_sizes, int n_in,
                              void* d_out, int out_size, void* d_ws, size_t ws_size,
                              hipStream_t stream) {
    const int*   ct0    = (const int*)d_in[0];
    const int*   cts    = (const int*)d_in[1];
    const int*   y      = (const int*)d_in[2];
    const int*   sk_y   = (const int*)d_in[3];
    const float* bias1  = (const float*)d_in[4];
    const float* bn1_g  = (const float*)d_in[5];
    const float* bn1_b  = (const float*)d_in[6];
    const float* bn1_m  = (const float*)d_in[7];
    const float* bn1_v  = (const float*)d_in[8];
    const float* conv2_w = (const float*)d_in[9];
    const float* conv2_b = (const float*)d_in[10];
    const float* bn2_g  = (const float*)d_in[11];
    const float* bn2_b  = (const float*)d_in[12];
    const float* bn2_m  = (const float*)d_in[13];
    const float* bn2_v  = (const float*)d_in[14];
    const float* conv3_w = (const float*)d_in[15];
    const float* conv3_b = (const float*)d_in[16];
    const float* bn3_g  = (const float*)d_in[17];
    const float* bn3_b  = (const float*)d_in[18];
    const float* bn3_m  = (const float*)d_in[19];
    const float* bn3_v  = (const float*)d_in[20];
    const float* fc1_w  = (const float*)d_in[21];
    const float* fc1_b  = (const float*)d_in[22];
    const float* fc2_w  = (const float*)d_in[23];
    const float* fc2_b  = (const float*)d_in[24];
    const int*   g_in   = (const int*)d_in[25];
    float* out = (float*)d_out;

    // Workspace layout (bytes):
    //   [0,        2000006)  int16 dlog table (p entries)
    //   [2000064,  2000068)  unsigned barrier counter (re-zeroed by build_table)
    //   [2000128,  2200832)  float featr [4][16][28][28]
    //   [2200832,  2225920)  float s2g   [4][32][7][7]
    //   [2225920,  2235136)  float s3g   [4][576]
    char* ws = (char*)d_ws;
    int16_t*  table = (int16_t*)ws;
    unsigned* ctr   = (unsigned*)(ws + 2000064);
    float* featr = (float*)(ws + 2000128);
    float* s2g   = (float*)(ws + 2200832);
    float* s3g   = (float*)(ws + 2225920);

    build_table<<<(TBLN + 255) / 256, 256, 0, stream>>>(g_in, table, ctr);

    fused<<<NBLK, 256, 0, stream>>>(
        ct0, cts, y, sk_y, bias1, bn1_g, bn1_b, bn1_m, bn1_v,
        conv2_w, conv2_b, bn2_g, bn2_b, bn2_m, bn2_v,
        conv3_w, conv3_b, bn3_g, bn3_b, bn3_m, bn3_v,
        fc1_w, fc1_b, fc2_w, fc2_b, table, featr, s2g, s3g, out, ctr);
}

// Round 3
// 131.200 us; speedup vs baseline: 1.3854x; 1.2077x over previous
//
#include <hip/hip_runtime.h>
#include <stdint.h>

#define PRIME 1000003u
#define NORD  1000002u
#define KCH   16
#define BATCH 4
#define NPATCH 784
#define LLEN  9
#define IPMAX 9000          // |<x,y>| <= 20*50*9
#define TBLN  (2*IPMAX+1)
#define NBLK  128           // fused grid (all co-resident; 128 < 256 CUs)
#define ABLK  64            // decrypt blocks = (k,b) pairs
#define TPB   832           // 13 waves: covers 784 decrypt lanes

// Workspace offsets (bytes)
#define CTR_OFF   2000064   // 8 counters, 64B apart
#define POOL_OFF  2001024   // float pooled [4][16][14][14]  (50176 B)
#define S2G_OFF   2051200   // float s2g    [4][32][7][7]    (25088 B)
#define S3G_OFF   2076288   // float s3g    [4][576]         (9216 B)
#define HG_OFF    2085504   // float hg     [4][128]         (2048 B)

// Barrett: M = floor(2^41/p) = 2199016; exact for t < 2^40 with one cond-sub.
__device__ __forceinline__ uint32_t mmul(uint32_t a, uint32_t b) {
    uint64_t t = (uint64_t)a * (uint64_t)b;
    uint32_t q = (uint32_t)((t * 2199016ull) >> 41);
    uint32_t r = (uint32_t)t - q * PRIME;
    return (r >= PRIME) ? r - PRIME : r;
}

__device__ __forceinline__ uint32_t mpow(uint32_t base, uint32_t exp) {
    uint32_t r = 1u, b = base;
    while (exp) {
        if (exp & 1u) r = mmul(r, b);
        b = mmul(b, b);
        exp >>= 1;
    }
    return r;
}

// ---- Fence-free cross-phase data access (validated round 2: absmax 0) ------
// Relaxed agent-scope atomics compile to coherent (L2-bypassing) accesses.
// Stores are at the device coherence point once vmcnt retires them, which
// __syncthreads() waits for; loads cannot hit a stale local L2.
__device__ __forceinline__ void cstore(float* p, float v) {
    __hip_atomic_store(p, v, __ATOMIC_RELAXED, __HIP_MEMORY_SCOPE_AGENT);
}
__device__ __forceinline__ float cload(const float* p) {
    return __hip_atomic_load(p, __ATOMIC_RELAXED, __HIP_MEMORY_SCOPE_AGENT);
}

// ---- Grid barrier with 8-way-split arrival counters ------------------------
// Round-2 fit: same-cacheline coherent RMWs serialize at ~100ns each
// (196 arrivals to one line ~= 20us). Splitting arrivals across 8 lines
// (64B apart) cuts serialization 8x; <=16 RMWs/line/barrier ~= 1-2us.
// Counters are cumulative and monotone; waiters poll the 8-line sum.
__device__ __forceinline__ void arrive8(unsigned* ctrs, int bid) {
    __syncthreads();   // all block stores issued+retired (vmcnt 0) before add
    if (threadIdx.x == 0)
        __hip_atomic_fetch_add(&ctrs[(bid & 7) * 16], 1u,
                               __ATOMIC_RELAXED, __HIP_MEMORY_SCOPE_AGENT);
}
__device__ __forceinline__ void wait8(unsigned* ctrs, unsigned target) {
    if (threadIdx.x == 0) {
        for (;;) {
            unsigned s = 0;
#pragma unroll
            for (int i = 0; i < 8; i++)
                s += __hip_atomic_load(&ctrs[i * 16],
                                       __ATOMIC_RELAXED, __HIP_MEMORY_SCOPE_AGENT);
            if (s >= target) break;
            __builtin_amdgcn_s_sleep(8);
        }
    }
    __syncthreads();
}

// ---------------- Kernel 1: dlog lookup table (int16) -----------------------
// table[g^e mod p] = e for e in [-9000,9000]. Only queried entries are ever
// written (decrypted values are guaranteed g^e). Also zeroes the 8 barrier
// counters (ws is re-poisoned between iterations; the kernel boundary orders
// the zeroing before the fused kernel).
__global__ void build_table(const int* __restrict__ g_in, int16_t* __restrict__ table,
                            unsigned* __restrict__ ctrs) {
    int e = blockIdx.x * blockDim.x + threadIdx.x;
    if (e >= TBLN) return;
    if (e < 8)
        __hip_atomic_store(&ctrs[e * 16], 0u, __ATOMIC_RELAXED, __HIP_MEMORY_SCOPE_AGENT);
    int es = e - IPMAX;
    uint32_t exp = (es >= 0) ? (uint32_t)es : (uint32_t)(es + (int)NORD);
    table[mpow((uint32_t)g_in[0], exp)] = (int16_t)es;
}

// ---------------- Kernel 2: fused pipeline ----------------------------------
// 128 blocks x 832 threads. Phases / arrivals (cumulative targets):
//   A : decrypt+bn1+relu+pool(28->14), block=(k,b)   blocks 0..63   -> 64
//   B : conv2+bn2+relu+pool(14->7),    block=(b,oc)  blocks 0..127  -> 192
//   C : conv3+bn3+relu+pool(7->3), 4oc/block         blocks 0..63   -> 256
//   D1: fc1+relu, 8 outputs/block                    blocks 0..63   -> 320
//   D2: fc2                                          blocks 0..3
__global__ void __launch_bounds__(TPB) fused(
    const int* __restrict__ ct0, const int* __restrict__ cts,
    const int* __restrict__ y, const int* __restrict__ sk_y,
    const float* __restrict__ bias1,
    const float* __restrict__ bn1_g, const float* __restrict__ bn1_b,
    const float* __restrict__ bn1_m, const float* __restrict__ bn1_v,
    const float* __restrict__ conv2_w, const float* __restrict__ conv2_b,
    const float* __restrict__ bn2_g, const float* __restrict__ bn2_b,
    const float* __restrict__ bn2_m, const float* __restrict__ bn2_v,
    const float* __restrict__ conv3_w, const float* __restrict__ conv3_b,
    const float* __restrict__ bn3_g, const float* __restrict__ bn3_b,
    const float* __restrict__ bn3_m, const float* __restrict__ bn3_v,
    const float* __restrict__ fc1_w, const float* __restrict__ fc1_b,
    const float* __restrict__ fc2_w, const float* __restrict__ fc2_b,
    const int16_t* __restrict__ table,
    float* __restrict__ pooled, float* __restrict__ s2g, float* __restrict__ s3g,
    float* __restrict__ hg, float* __restrict__ out, unsigned* __restrict__ ctrs) {

    __shared__ union {
        float raw[784];                                                        // A: 3.1 KB
        struct { float s1p[16][16][16]; float w[144]; float co[196]; } c2;     // 17.7 KB
        struct { float s2p[32][9][9];  float w[4][288]; float co[4][49]; } c3; // 15.8 KB
        struct { float s3[576]; } d1;
        struct { float h[128]; } d2;
    } sm;

    const int bid = blockIdx.x;
    const int tid = threadIdx.x;

    // ---------------- Phase A: decrypt + bn1 + relu + pool(28->14) ---------
    // block = (k,b): k,b,sk,y-row,bn1 params all BLOCK-uniform -> scalar.
    // 13 waves/CU on 64 CUs (3.25/SIMD) overlap the serial mmul chains.
    if (bid < ABLK) {
        const int k = bid & 15, b = bid >> 4;
        const int* yrow = y + k * LLEN;
        int yv[LLEN];
#pragma unroll
        for (int i = 0; i < LLEN; i++) yv[i] = yrow[i];      // scalar loads
        const uint32_t sk = (uint32_t)sk_y[k];
        const float sc  = bn1_g[k] * rsqrtf(bn1_v[k] + 1e-5f);
        const float shf = (bias1[k] - bn1_m[k]) * sc + bn1_b[k];

        if (tid < NPATCH) {
            const int j = tid;
            const int* crow = cts + ((b * NPATCH) + j) * LLEN;
            uint32_t c[LLEN];
#pragma unroll
            for (int i = 0; i < LLEN; i++) c[i] = (uint32_t)crow[i];

            // Shamir: |y_i| <= 50 < 64 (6 bits). Branch conds block-uniform.
            uint32_t accp = 1u, accn = 1u;
#pragma unroll
            for (int bit = 5; bit >= 0; bit--) {
                accp = mmul(accp, accp);
                accn = mmul(accn, accn);
#pragma unroll
                for (int i = 0; i < LLEN; i++) {
                    int yi = yv[i];
                    int ay = (yi > 0) ? yi : -yi;
                    if ((ay >> bit) & 1) {
                        if (yi > 0) accp = mmul(accp, c[i]);
                        else        accn = mmul(accn, c[i]);
                    }
                }
            }

            uint32_t den = mpow((uint32_t)ct0[b * NPATCH + j], sk);
            den = mmul(den, accn);
            uint32_t val = mmul(accp, mpow(den, PRIME - 2u));  // const exp: unrolls

            int ip = (int)table[val];              // guaranteed hit, |ip|<=9000
            float v_ = fmaf((float)ip, sc * 1e-4f, shf);
            sm.raw[j] = fmaxf(v_, 0.0f);
        }
        __syncthreads();
        if (tid < 196) {
            int py = tid / 14, px = tid % 14;
            const float* r0 = &sm.raw[(2 * py) * 28 + 2 * px];
            float m = fmaxf(fmaxf(r0[0], r0[1]), fmaxf(r0[28], r0[29]));
            cstore(&pooled[((b * KCH) + k) * 196 + tid], m);
        }
        arrive8(ctrs, bid);                 // -> 64
    }

    wait8(ctrs, ABLK);

    // ---------------- Phase B: conv2 + bn2 + relu + pool(14->7) ------------
    {
        const int b  = bid >> 5;
        const int oc = bid & 31;

        for (int i = tid; i < 16 * 16 * 16; i += TPB)
            ((float*)sm.c2.s1p)[i] = 0.0f;
        if (tid < 144) sm.c2.w[tid] = conv2_w[oc * 144 + tid];
        __syncthreads();
        for (int i = tid; i < 16 * 196; i += TPB) {
            int ic = i / 196, pos = i % 196;
            int yy = pos / 14, xx = pos % 14;
            sm.c2.s1p[ic][yy + 1][xx + 1] = cload(&pooled[((b * KCH) + ic) * 196 + pos]);
        }
        __syncthreads();

        if (tid < 196) {
            int oh = tid / 14, ow = tid % 14;
            float a0 = 0.0f, a1 = 0.0f, a2 = 0.0f;
#pragma unroll
            for (int ic = 0; ic < 16; ic++) {
                const float* wp = &sm.c2.w[ic * 9];
                const float* sp = &sm.c2.s1p[ic][oh][ow];
                a0 = fmaf(sp[0],  wp[0], fmaf(sp[1],  wp[1], fmaf(sp[2],  wp[2], a0)));
                a1 = fmaf(sp[16], wp[3], fmaf(sp[17], wp[4], fmaf(sp[18], wp[5], a1)));
                a2 = fmaf(sp[32], wp[6], fmaf(sp[33], wp[7], fmaf(sp[34], wp[8], a2)));
            }
            float sc = bn2_g[oc] * rsqrtf(bn2_v[oc] + 1e-5f);
            float shf = bn2_b[oc] - bn2_m[oc] * sc;
            sm.c2.co[tid] = fmaxf((a0 + a1 + a2 + conv2_b[oc]) * sc + shf, 0.0f);
        }
        __syncthreads();

        if (tid < 49) {
            int oh = tid / 7, ow = tid % 7;
            const float* c0 = &sm.c2.co[(2 * oh) * 14 + 2 * ow];
            cstore(&s2g[((b * 32 + oc) * 49) + tid],
                   fmaxf(fmaxf(c0[0], c0[1]), fmaxf(c0[14], c0[15])));
        }
    }

    arrive8(ctrs, bid);                     // -> 192
    if (bid >= 64) return;
    wait8(ctrs, ABLK + NBLK);

    // ---------------- Phase C: conv3 + bn3 + relu + pool (4 oc / block) ----
    {
        const int b = bid >> 4, ocg = bid & 15;

        for (int i = tid; i < 32 * 81; i += TPB)
            ((float*)sm.c3.s2p)[i] = 0.0f;
        for (int i = tid; i < 4 * 288; i += TPB) {
            int w2 = i / 288, rr = i % 288;
            sm.c3.w[w2][rr] = conv3_w[(ocg * 4 + w2) * 288 + rr];
        }
        __syncthreads();
        for (int i = tid; i < 32 * 49; i += TPB) {
            int ic = i / 49, pos = i % 49;
            sm.c3.s2p[ic][pos / 7 + 1][pos % 7 + 1] = cload(&s2g[((b * 32 + ic) * 49) + pos]);
        }
        __syncthreads();

        const int wid = tid >> 6, lane = tid & 63;
        if (wid < 4 && lane < 49) {
            int oh = lane / 7, ow = lane % 7;
            float a0 = 0.0f, a1 = 0.0f, a2 = 0.0f;
#pragma unroll
            for (int ic = 0; ic < 32; ic++) {
                const float* wp = &sm.c3.w[wid][ic * 9];
                const float* sp = &sm.c3.s2p[ic][oh][ow];
                a0 = fmaf(sp[0],  wp[0], fmaf(sp[1],  wp[1], fmaf(sp[2],  wp[2], a0)));
                a1 = fmaf(sp[9],  wp[3], fmaf(sp[10], wp[4], fmaf(sp[11], wp[5], a1)));
                a2 = fmaf(sp[18], wp[6], fmaf(sp[19], wp[7], fmaf(sp[20], wp[8], a2)));
            }
            int oc = ocg * 4 + wid;
            float sc = bn3_g[oc] * rsqrtf(bn3_v[oc] + 1e-5f);
            float shf = bn3_b[oc] - bn3_m[oc] * sc;
            sm.c3.co[wid][lane] = fmaxf((a0 + a1 + a2 + conv3_b[oc]) * sc + shf, 0.0f);
        }
        __syncthreads();

        if (tid < 36) {
            int w2 = tid / 9, p = tid % 9;
            int oh = p / 3, ow = p % 3;
            const float* c0 = &sm.c3.co[w2][(2 * oh) * 7 + 2 * ow];
            cstore(&s3g[b * 576 + (ocg * 4 + w2) * 9 + p],
                   fmaxf(fmaxf(c0[0], c0[1]), fmaxf(c0[7], c0[8])));
        }
    }

    arrive8(ctrs, bid);                     // -> 256
    wait8(ctrs, ABLK + NBLK + 64);

    // ---------------- Phase D1: fc1 + relu (8 outputs / block) -------------
    // 64 blocks: fc1_w read once per batch in parallel, 9 loads/thread.
    {
        const int b = bid >> 4, og = bid & 15;
        for (int i = tid; i < 576; i += TPB) sm.d1.s3[i] = cload(&s3g[b * 576 + i]);
        __syncthreads();

        const int wid = tid >> 6, lane = tid & 63;
        if (wid < 8) {
            int o = og * 8 + wid;
            const float* w = fc1_w + o * 576;
            float acc = 0.0f;
#pragma unroll
            for (int jj = 0; jj < 9; jj++)     // lanes across 576: coalesced
                acc = fmaf(sm.d1.s3[jj * 64 + lane], w[jj * 64 + lane], acc);
#pragma unroll
            for (int off = 32; off; off >>= 1) acc += __shfl_down(acc, off);
            if (lane == 0) cstore(&hg[b * 128 + o], fmaxf(acc + fc1_b[o], 0.0f));
        }
    }

    arrive8(ctrs, bid);                     // -> 320
    if (bid >= BATCH) return;
    wait8(ctrs, ABLK + NBLK + 64 + 64);

    // ---------------- Phase D2: fc2 ----------------------------------------
    {
        const int b = bid;
        if (tid < 128) sm.d2.h[tid] = cload(&hg[b * 128 + tid]);
        __syncthreads();

        const int wid = tid >> 6, lane = tid & 63;
        if (wid < 10) {
            const float* w = fc2_w + wid * 128;
            float acc = fmaf(sm.d2.h[lane], w[lane], 0.0f);
            acc = fmaf(sm.d2.h[64 + lane], w[64 + lane], acc);
#pragma unroll
            for (int off = 32; off; off >>= 1) acc += __shfl_down(acc, off);
            if (lane == 0) out[b * 10 + wid] = acc + fc2_b[wid];
        }
    }
}

extern "C" void kernel_launch(void* const* d_in, const int* in_sizes, int n_in,
                              void* d_out, int out_size, void* d_ws, size_t ws_size,
                              hipStream_t stream) {
    const int*   ct0    = (const int*)d_in[0];
    const int*   cts    = (const int*)d_in[1];
    const int*   y      = (const int*)d_in[2];
    const int*   sk_y   = (const int*)d_in[3];
    const float* bias1  = (const float*)d_in[4];
    const float* bn1_g  = (const float*)d_in[5];
    const float* bn1_b  = (const float*)d_in[6];
    const float* bn1_m  = (const float*)d_in[7];
    const float* bn1_v  = (const float*)d_in[8];
    const float* conv2_w = (const float*)d_in[9];
    const float* conv2_b = (const float*)d_in[10];
    const float* bn2_g  = (const float*)d_in[11];
    const float* bn2_b  = (const float*)d_in[12];
    const float* bn2_m  = (const float*)d_in[13];
    const float* bn2_v  = (const float*)d_in[14];
    const float* conv3_w = (const float*)d_in[15];
    const float* conv3_b = (const float*)d_in[16];
    const float* bn3_g  = (const float*)d_in[17];
    const float* bn3_b  = (const float*)d_in[18];
    const float* bn3_m  = (const float*)d_in[19];
    const float* bn3_v  = (const float*)d_in[20];
    const float* fc1_w  = (const float*)d_in[21];
    const float* fc1_b  = (const float*)d_in[22];
    const float* fc2_w  = (const float*)d_in[23];
    const float* fc2_b  = (const float*)d_in[24];
    const int*   g_in   = (const int*)d_in[25];
    float* out = (float*)d_out;

    char* ws = (char*)d_ws;
    int16_t*  table  = (int16_t*)ws;
    unsigned* ctrs   = (unsigned*)(ws + CTR_OFF);
    float* pooled = (float*)(ws + POOL_OFF);
    float* s2g    = (float*)(ws + S2G_OFF);
    float* s3g    = (float*)(ws + S3G_OFF);
    float* hg     = (float*)(ws + HG_OFF);

    build_table<<<(TBLN + 255) / 256, 256, 0, stream>>>(g_in, table, ctrs);

    fused<<<NBLK, TPB, 0, stream>>>(
        ct0, cts, y, sk_y, bias1, bn1_g, bn1_b, bn1_m, bn1_v,
        conv2_w, conv2_b, bn2_g, bn2_b, bn2_m, bn2_v,
        conv3_w, conv3_b, bn3_g, bn3_b, bn3_m, bn3_v,
        fc1_w, fc1_b, fc2_w, fc2_b, table, pooled, s2g, s3g, hg, out, ctrs);
}